// Round 5
// baseline (310.278 us; speedup 1.0000x reference)
//
#include <hip/hip_runtime.h>

typedef unsigned short u16;
typedef __attribute__((ext_vector_type(8))) short bf16x8;
typedef __attribute__((ext_vector_type(4))) float f32x4;
typedef __attribute__((ext_vector_type(4))) int i32x4;
typedef __attribute__((ext_vector_type(2))) int i32x2;

#define N_PTS   65536
#define CH_DIM  256
#define BATCH   8
#define KTOK    256
#define CTX_DIM 768
#define NHEAD   8
#define HD      64
#define HDIM    512   // NHEAD*HD
#define NPB     8192  // N_PTS/BATCH

__device__ __forceinline__ u16 f2bf(float f) {
    union { float f; unsigned u; } v; v.f = f;
    unsigned r = v.u + 0x7fffu + ((v.u >> 16) & 1u);
    return (u16)(r >> 16);
}
// HW packed f32->bf16 (RNE), 1 instr for a pair.
__device__ __forceinline__ unsigned cvtpk(float lo, float hi) {
    unsigned r;
    asm("v_cvt_pk_bf16_f32 %0, %1, %2" : "=v"(r) : "v"(lo), "v"(hi));
    return r;
}
// bare v_exp_f32 (base-2 exponential)
__device__ __forceinline__ float exp2_hw(float x) {
    float r;
    asm("v_exp_f32 %0, %1" : "=v"(r) : "v"(x));
    return r;
}
__device__ __forceinline__ float max3f(float a, float b, float c) {
    float r;
    asm("v_max3_f32 %0, %1, %2, %3" : "=v"(r) : "v"(a), "v"(b), "v"(c));
    return r;
}

// async global->LDS, 16B per lane. HW writes lane i at wave-uniform base + i*16.
__device__ __forceinline__ void gll16(const void* g, void* l) {
    __builtin_amdgcn_global_load_lds(
        (const __attribute__((address_space(1))) void*)g,
        (__attribute__((address_space(3))) void*)l, 16, 0, 0);
}

// ---------------------------------------------------------------------------
// convk: fp32 -> bf16, 8 elems/thread/iter, HW pack converts.
// ---------------------------------------------------------------------------
__global__ void convk(const float* __restrict__ src, u16* __restrict__ dst, int n8) {
    int i = blockIdx.x * blockDim.x + threadIdx.x;
    int st = gridDim.x * blockDim.x;
    for (; i < n8; i += st) {
        const float* p = src + (size_t)i * 8;
        f32x4 a = *(const f32x4*)p;
        f32x4 b = *(const f32x4*)(p + 4);
        i32x4 o;
        o[0] = (int)cvtpk(a[0], a[1]);
        o[1] = (int)cvtpk(a[2], a[3]);
        o[2] = (int)cvtpk(b[0], b[1]);
        o[3] = (int)cvtpk(b[2], b[3]);
        *(i32x4*)&dst[(size_t)i * 8] = o;
    }
}

// ---------------------------------------------------------------------------
// tconvk: W[R][C] fp32 -> WT[C][R] bf16. Flat: dst[i] = src[(i%R)*C + i/R].
// ---------------------------------------------------------------------------
__global__ void tconvk(const float* __restrict__ W, u16* __restrict__ WT, int R, int C) {
    int i = blockIdx.x * blockDim.x + threadIdx.x;
    if (i >= R * C) return;
    WT[i] = f2bf(W[(size_t)(i % R) * C + i / R]);
}

// tconv3k: fused Wq/Wk/Wv transpose+convert (one launch instead of three).
__global__ void tconv3k(const float* __restrict__ Wq, const float* __restrict__ Wk,
                        const float* __restrict__ Wv,
                        u16* __restrict__ WqT, u16* __restrict__ WkvT) {
    int i = blockIdx.x * blockDim.x + threadIdx.x;
    if (i < 131072) {
        WqT[i] = f2bf(Wq[(size_t)(i % 256) * 512 + i / 256]);
    } else if (i < 524288) {
        int j = i - 131072;
        WkvT[j] = f2bf(Wk[(size_t)(j % 768) * 512 + j / 768]);
    } else if (i < 917504) {
        int j = i - 524288;
        WkvT[393216 + j] = f2bf(Wv[(size_t)(j % 768) * 512 + j / 768]);
    }
}

// ---------------------------------------------------------------------------
// gemm_bt, depth-3 counted-vmcnt pipeline (T4): C(MxN) = A(MxK) @ BT(NxK)^T.
// 128x128 tile, BK=32, 4 waves 2x2, 4x4 frags/wave, KC compile-time.
// 3 LDS buffers; prologue stages tiles 0..2; per iter: wait vmcnt(8)
// (tile t landed, t+1/t+2 STAY IN FLIGHT across both barriers -- never
// drain to 0 in-loop), barrier, compute t, barrier (release buf), stage t+3.
// Tail iters wait vmcnt(4)/vmcnt(0). Full unroll -> static buffers/waits.
//   OUT_F32: fp32 out + fp32 bias/resid epilogue, else bf16 out (x oscale).
//   VT_OUT:  (v-proj style) transposed+permuted C write (see attn_mfma).
// T1 XCD swizzle: bijective remap (all grids here have nwg % 8 == 0).
// LDS 48 KB -> 3 blocks/CU.
// ---------------------------------------------------------------------------
template <int KC, bool OUT_F32, bool VT_OUT>
__global__ __launch_bounds__(256, 3) void gemm_bt(
    const u16* __restrict__ A, const u16* __restrict__ BT, void* __restrict__ Cv,
    int M, int N,
    const float* __restrict__ bias, const float* __restrict__ resid, float oscale)
{
    constexpr int NT = KC / 32;
    static_assert(NT >= 3, "need >=3 K-tiles");
    __shared__ __align__(16) u16 As[3][128 * 32];   // 3 x 8 KB
    __shared__ __align__(16) u16 Bs[3][128 * 32];   // 3 x 8 KB

    const int tid  = threadIdx.x;
    const int lane = tid & 63;
    const int w    = tid >> 6;
    const int wm   = w & 1;
    const int wn   = w >> 1;

    const int nwg = gridDim.x * gridDim.y;
    const int wg  = blockIdx.y * gridDim.x + blockIdx.x;
    const int swz = (wg & 7) * (nwg >> 3) + (wg >> 3);
    const int n0  = (swz % gridDim.x) * 128;
    const int m0  = (swz / gridDim.x) * 128;

    const int l15  = lane & 15;
    const int quad = lane >> 4;

    f32x4 acc[4][4];
#pragma unroll
    for (int i = 0; i < 4; i++)
#pragma unroll
        for (int j = 0; j < 4; j++) { acc[i][j][0]=0.f; acc[i][j][1]=0.f; acc[i][j][2]=0.f; acc[i][j][3]=0.f; }

    const int sr = tid >> 2;
    const int sc = (tid & 3) * 8;
    const u16* Abase = A  + (size_t)(m0 + sr) * KC + sc;
    const u16* Bbase = BT + (size_t)(n0 + sr) * KC + sc;
    const size_t rowStep = (size_t)64 * KC;
    const int d8 = tid * 8;

    auto stage = [&](int t, int buf) {
        const u16* Ap = Abase + t * 32;
        const u16* Bp = Bbase + t * 32;
        gll16(Ap,           &As[buf][d8]);
        gll16(Ap + rowStep, &As[buf][d8 + 2048]);
        gll16(Bp,           &Bs[buf][d8]);
        gll16(Bp + rowStep, &Bs[buf][d8 + 2048]);
    };

    // ---- prologue: tiles 0..2 in flight (12 loads) ----
    stage(0, 0); stage(1, 1); stage(2, 2);

#pragma unroll
    for (int t = 0; t < NT; ++t) {
        const int rem = NT - 1 - t;
        if (rem >= 2)      asm volatile("s_waitcnt vmcnt(8)" ::: "memory");
        else if (rem == 1) asm volatile("s_waitcnt vmcnt(4)" ::: "memory");
        else               asm volatile("s_waitcnt vmcnt(0)" ::: "memory");
        __builtin_amdgcn_sched_barrier(0);
        __builtin_amdgcn_s_barrier();          // everyone's tile-t data in LDS
        __builtin_amdgcn_sched_barrier(0);

        const int buf = t % 3;
        bf16x8 af[4], bfr[4];
#pragma unroll
        for (int rt = 0; rt < 4; rt++)
            af[rt] = *(const bf16x8*)&As[buf][(wm * 64 + rt * 16 + l15) * 32 + quad * 8];
#pragma unroll
        for (int nt = 0; nt < 4; nt++)
            bfr[nt] = *(const bf16x8*)&Bs[buf][(wn * 64 + nt * 16 + l15) * 32 + quad * 8];
#pragma unroll
        for (int rt = 0; rt < 4; rt++)
#pragma unroll
            for (int nt = 0; nt < 4; nt++)
                acc[rt][nt] = __builtin_amdgcn_mfma_f32_16x16x32_bf16(af[rt], bfr[nt], acc[rt][nt], 0, 0, 0);

        __builtin_amdgcn_sched_barrier(0);
        __builtin_amdgcn_s_barrier();          // release buf[t%3]
        __builtin_amdgcn_sched_barrier(0);
        if (t + 3 < NT) stage(t + 3, buf);     // overwrite released buffer
    }

    if (VT_OUT) {
        u16* CT = (u16*)Cv;
#pragma unroll
        for (int nt = 0; nt < 4; nt++) {
            int col = n0 + wn * 64 + nt * 16 + l15;   // h*64 + d
            int hh = col >> 6, dd = col & 63;
#pragma unroll
            for (int rt = 0; rt < 4; rt++) {
                int row = m0 + wm * 64 + rt * 16 + quad * 4;  // b*256 + t
                int bb = row >> 8, jb = row & 255;
                int jp = (jb & 0xE0) | ((jb & 0x0C) << 1) | ((jb & 0x10) >> 2);
                union { unsigned u[2]; i32x2 q; } pk;
                pk.u[0] = cvtpk(acc[rt][nt][0], acc[rt][nt][1]);
                pk.u[1] = cvtpk(acc[rt][nt][2], acc[rt][nt][3]);
                *(i32x2*)&CT[(((size_t)(bb * 8 + hh)) * 64 + dd) * 256 + jp] = pk.q;
            }
        }
    } else {
#pragma unroll
        for (int nt = 0; nt < 4; nt++) {
            int col = n0 + wn * 64 + nt * 16 + l15;
            float bv = bias ? bias[col] : 0.0f;
#pragma unroll
            for (int rt = 0; rt < 4; rt++) {
#pragma unroll
                for (int r = 0; r < 4; r++) {
                    int row = m0 + wm * 64 + rt * 16 + quad * 4 + r;
                    float v = acc[rt][nt][r] + bv;
                    if (resid) v += resid[(size_t)row * N + col];
                    if (OUT_F32) ((float*)Cv)[(size_t)row * N + col] = v;
                    else         ((u16*)Cv)[(size_t)row * N + col]   = f2bf(v * oscale);
                }
            }
        }
    }
}

// ---------------------------------------------------------------------------
// gemm_kv: fused K-proj + V-proj, depth-3 counted-vmcnt pipeline.
// A = cb [2048][768], BT = WkvT [1024][768] (rows 0..511 Wk, 512..1023 Wv).
// 64x64 tile, 4 waves 2x2, BK=32, NT=24, 2 loads/thread/tile ->
// waits vmcnt(4)/(2)/(0). Grid 16x32 = 512 blocks. Block-uniform epilogue:
//   n0 <  512 -> kbuf[row*512 + col]
//   n0 >= 512 -> vbufT transposed+permuted write (attn PV layout).
// LDS 24 KB -> 4+ blocks/CU.
// ---------------------------------------------------------------------------
__global__ __launch_bounds__(256, 4) void gemm_kv(
    const u16* __restrict__ A, const u16* __restrict__ BT,
    u16* __restrict__ kd, u16* __restrict__ vtd)
{
    constexpr int KC = CTX_DIM;
    constexpr int NT = KC / 32;   // 24
    __shared__ __align__(16) u16 As[3][64 * 32];   // 3 x 4 KB
    __shared__ __align__(16) u16 Bs[3][64 * 32];   // 3 x 4 KB

    const int tid  = threadIdx.x;
    const int lane = tid & 63;
    const int w    = tid >> 6;
    const int wm   = w & 1;
    const int wn   = w >> 1;

    const int nwg = gridDim.x * gridDim.y;          // 512
    const int wg  = blockIdx.y * gridDim.x + blockIdx.x;
    const int swz = (wg & 7) * (nwg >> 3) + (wg >> 3);
    const int n0  = (swz % gridDim.x) * 64;
    const int m0  = (swz / gridDim.x) * 64;

    const int l15  = lane & 15;
    const int quad = lane >> 4;

    f32x4 acc[2][2];
#pragma unroll
    for (int i = 0; i < 2; i++)
#pragma unroll
        for (int j = 0; j < 2; j++) { acc[i][j][0]=0.f; acc[i][j][1]=0.f; acc[i][j][2]=0.f; acc[i][j][3]=0.f; }

    const int sr = tid >> 2;          // 0..63
    const int sc = (tid & 3) * 8;
    const u16* Abase = A  + (size_t)(m0 + sr) * KC + sc;
    const u16* Bbase = BT + (size_t)(n0 + sr) * KC + sc;
    const int d8 = tid * 8;

    auto stage = [&](int t, int buf) {
        gll16(Abase + t * 32, &As[buf][d8]);
        gll16(Bbase + t * 32, &Bs[buf][d8]);
    };

    stage(0, 0); stage(1, 1); stage(2, 2);

#pragma unroll
    for (int t = 0; t < NT; ++t) {
        const int rem = NT - 1 - t;
        if (rem >= 2)      asm volatile("s_waitcnt vmcnt(4)" ::: "memory");
        else if (rem == 1) asm volatile("s_waitcnt vmcnt(2)" ::: "memory");
        else               asm volatile("s_waitcnt vmcnt(0)" ::: "memory");
        __builtin_amdgcn_sched_barrier(0);
        __builtin_amdgcn_s_barrier();
        __builtin_amdgcn_sched_barrier(0);

        const int buf = t % 3;
        bf16x8 af[2], bfr[2];
#pragma unroll
        for (int rt = 0; rt < 2; rt++)
            af[rt] = *(const bf16x8*)&As[buf][(wm * 32 + rt * 16 + l15) * 32 + quad * 8];
#pragma unroll
        for (int nt = 0; nt < 2; nt++)
            bfr[nt] = *(const bf16x8*)&Bs[buf][(wn * 32 + nt * 16 + l15) * 32 + quad * 8];
#pragma unroll
        for (int rt = 0; rt < 2; rt++)
#pragma unroll
            for (int nt = 0; nt < 2; nt++)
                acc[rt][nt] = __builtin_amdgcn_mfma_f32_16x16x32_bf16(af[rt], bfr[nt], acc[rt][nt], 0, 0, 0);

        __builtin_amdgcn_sched_barrier(0);
        __builtin_amdgcn_s_barrier();
        __builtin_amdgcn_sched_barrier(0);
        if (t + 3 < NT) stage(t + 3, buf);
    }

    if (n0 < 512) {   // ---- K half: plain bf16 [2048][512] ----
#pragma unroll
        for (int nt = 0; nt < 2; nt++) {
            int col = n0 + wn * 32 + nt * 16 + l15;
#pragma unroll
            for (int rt = 0; rt < 2; rt++) {
#pragma unroll
                for (int r = 0; r < 4; r++) {
                    int row = m0 + wm * 32 + rt * 16 + quad * 4 + r;
                    kd[(size_t)row * HDIM + col] = f2bf(acc[rt][nt][r]);
                }
            }
        }
    } else {          // ---- V half: transposed + permuted (attn PV layout) ----
#pragma unroll
        for (int nt = 0; nt < 2; nt++) {
            int col = (n0 - 512) + wn * 32 + nt * 16 + l15;   // h*64 + d
            int hh = col >> 6, dd = col & 63;
#pragma unroll
            for (int rt = 0; rt < 2; rt++) {
                int row = m0 + wm * 32 + rt * 16 + quad * 4;  // b*256 + t
                int bb = row >> 8, jb = row & 255;
                int jp = (jb & 0xE0) | ((jb & 0x0C) << 1) | ((jb & 0x10) >> 2);
                union { unsigned u[2]; i32x2 q; } pk;
                pk.u[0] = cvtpk(acc[rt][nt][0], acc[rt][nt][1]);
                pk.u[1] = cvtpk(acc[rt][nt][2], acc[rt][nt][3]);
                *(i32x2*)&vtd[(((size_t)(bb * 8 + hh)) * 64 + dd) * 256 + jp] = pk.q;
            }
        }
    }
}

// ---------------------------------------------------------------------------
// MFMA attention, zero-shuffle P path (unchanged; see r2/r3 notes).
// ---------------------------------------------------------------------------
#define KS2 72    // Ks row stride (u16)
#define VS2 264   // Vt row stride (u16)
__global__ __launch_bounds__(256, 4) void attn_mfma(
    const u16* qbuf, const u16* __restrict__ kbuf,
    const u16* __restrict__ vbufT, const int* __restrict__ perm,
    u16* ft)
{
    __shared__ __align__(16) u16 smem[18432];   // 36864 B
    u16* Ks = smem;                              // phase 1 (256 x KS2)
    u16* Vt = smem;                              // phase 3 (64 x VS2, reuse)

    const int tid   = threadIdx.x;
    const int lane  = tid & 63;
    const int w     = tid >> 6;
    const int chunk = blockIdx.x;
    const int bh    = blockIdx.y;
    const int b     = bh >> 3;
    const int h     = bh & 7;
    const int l15   = lane & 15;
    const int quad  = lane >> 4;

    // ---- Q B-frags from global (gathered row, 16B contiguous); q = w*16+l15 ----
    const int prow = perm[b * NPB + chunk * 64 + w * 16 + l15];
    const u16* qrow = qbuf + (size_t)prow * HDIM + h * HD;
    bf16x8 qf0 = *(const bf16x8*)&qrow[quad * 8];
    bf16x8 qf1 = *(const bf16x8*)&qrow[32 + quad * 8];

    // ---- stage K_h (256x64) into LDS, b128 writes ----
    {
        const int j8 = tid >> 3;        // 0..31
        const int c  = (tid & 7) * 8;   // 0..56
#pragma unroll
        for (int pass = 0; pass < 8; pass++) {
            int jj = j8 + pass * 32;
            i32x4 val = *(const i32x4*)&kbuf[((size_t)(b * KTOK + jj)) * HDIM + h * HD + c];
            *(i32x4*)&Ks[jj * KS2 + c] = val;
        }
    }
    __syncthreads();

    // ---- phase 1: S^T = K @ Q^T ----
    f32x4 sc[16];
#pragma unroll
    for (int nt = 0; nt < 16; nt++) { sc[nt][0]=0.f; sc[nt][1]=0.f; sc[nt][2]=0.f; sc[nt][3]=0.f; }
#pragma unroll
    for (int nt = 0; nt < 16; nt++) {
        bf16x8 kf = *(const bf16x8*)&Ks[(nt * 16 + l15) * KS2 + quad * 8];
        sc[nt] = __builtin_amdgcn_mfma_f32_16x16x32_bf16(kf, qf0, sc[nt], 0, 0, 0);
    }
#pragma unroll
    for (int nt = 0; nt < 16; nt++) {
        bf16x8 kf = *(const bf16x8*)&Ks[(nt * 16 + l15) * KS2 + 32 + quad * 8];
        sc[nt] = __builtin_amdgcn_mfma_f32_16x16x32_bf16(kf, qf1, sc[nt], 0, 0, 0);
    }
    // sc[nt][r] = S'[k = nt*16 + quad*4 + r][q = w*16 + l15]  (log2-domain)

    // ---- phase 3a: issue V' loads to regs; latency hides under softmax ----
    i32x4 vreg[8];
    const u16* vslice = vbufT + ((size_t)(b * NHEAD + h)) * HD * KTOK;
    const int vrow = tid >> 2;          // d = 0..63
    const int vc0  = (tid & 3) * 8;
#pragma unroll
    for (int pass = 0; pass < 8; pass++)
        vreg[pass] = *(const i32x4*)&vslice[(size_t)vrow * KTOK + vc0 + pass * 32];

    // ---- phase 2: softmax (log2 domain), lane-local; deferred 1/s ----
    float m = -1e30f;
#pragma unroll
    for (int nt = 0; nt < 16; nt++) {
        f32x4 v = sc[nt];
        m = max3f(m, max3f(v[0], v[1], v[2]), v[3]);
    }
    m = fmaxf(m, __shfl_xor(m, 16));
    m = fmaxf(m, __shfl_xor(m, 32));
    float s0 = 0.f, s1 = 0.f, s2 = 0.f, s3 = 0.f;
#pragma unroll
    for (int nt = 0; nt < 16; nt++) {
        float e0 = exp2_hw(sc[nt][0] - m);
        float e1 = exp2_hw(sc[nt][1] - m);
        float e2 = exp2_hw(sc[nt][2] - m);
        float e3 = exp2_hw(sc[nt][3] - m);
        sc[nt][0] = e0; sc[nt][1] = e1; sc[nt][2] = e2; sc[nt][3] = e3;
        s0 += e0; s1 += e1; s2 += e2; s3 += e3;
    }
    float s = (s0 + s1) + (s2 + s3);
    s += __shfl_xor(s, 16);
    s += __shfl_xor(s, 32);
    float inv = 1.0f / s;

    // ---- pack P to bf16 pairs in-register (HW cvt_pk) ----
    unsigned up[16][2];
#pragma unroll
    for (int nt = 0; nt < 16; nt++) {
        up[nt][0] = cvtpk(sc[nt][0], sc[nt][1]);
        up[nt][1] = cvtpk(sc[nt][2], sc[nt][3]);
    }

    __syncthreads();   // all waves done reading Ks; region becomes Vt'

    // ---- phase 3b: store Vt' rows to LDS (contiguous b128) ----
#pragma unroll
    for (int pass = 0; pass < 8; pass++)
        *(i32x4*)&Vt[vrow * VS2 + vc0 + pass * 32] = vreg[pass];
    __syncthreads();

    // ---- phase 4: O = P V (A = P regs, B = Vt' b128 reads; 32 MFMA) ----
    f32x4 o[4];
#pragma unroll
    for (int n = 0; n < 4; n++) { o[n][0]=0.f; o[n][1]=0.f; o[n][2]=0.f; o[n][3]=0.f; }

#pragma unroll
    for (int ks = 0; ks < 8; ks++) {
        union { unsigned u[4]; bf16x8 v; } pb;
        pb.u[0] = up[2 * ks][0];
        pb.u[1] = up[2 * ks][1];
        pb.u[2] = up[2 * ks + 1][0];
        pb.u[3] = up[2 * ks + 1][1];
#pragma unroll
        for (int nt = 0; nt < 4; nt++) {
            bf16x8 bv = *(const bf16x8*)&Vt[(nt * 16 + l15) * VS2 + ks * 32 + quad * 8];
            o[nt] = __builtin_amdgcn_mfma_f32_16x16x32_bf16(pb.v, bv, o[nt], 0, 0, 0);
        }
    }
    // o[nt][r] = O~[q = w*16 + quad*4 + r][d = nt*16 + l15]  (unnormalized)

    // ---- phase 5: normalize + scatter O rows to ft[perm[q]] ----
#pragma unroll
    for (int r = 0; r < 4; r++) {
        float invq = __shfl(inv,  quad * 4 + r);
        int   po   = __shfl(prow, quad * 4 + r);
        u16* frow = ft + (size_t)po * HDIM + h * HD;
        unsigned pa = cvtpk(o[0][r] * invq, o[1][r] * invq);
        unsigned pb = cvtpk(o[2][r] * invq, o[3][r] * invq);
        frow[l15]      = (u16)pa;
        frow[16 + l15] = (u16)(pa >> 16);
        frow[32 + l15] = (u16)pb;
        frow[48 + l15] = (u16)(pb >> 16);
    }
}

// ---------------------------------------------------------------------------
// Launch. Workspace (unchanged 71303168 B):
//   ws+0        kbuf  [2048][512] bf16          (2 MB)
//   ws+2097152  vbufT [b][h][d][c'] bf16        (2 MB)  -> WoutT after attn
//   ws+4194304  qbuf/ft [65536][512] bf16       (67 MB)
// Scratch in d_out (all dead before the final gemm writes d_out):
//   +0         xb   [65536][256] bf16  (33554432)
//   +33554432  cb   [2048][768]  bf16  (3145728, ends 36700160)
//   +36700160  WkvT [1024][768]  bf16  (1572864, ends 38273024)
//   +38273024  WqT  [512][256]   bf16  (262144,  ends 38535168 < 67108864)
// ---------------------------------------------------------------------------
extern "C" void kernel_launch(void* const* d_in, const int* in_sizes, int n_in,
                              void* d_out, int out_size, void* d_ws, size_t ws_size,
                              hipStream_t stream) {
    const float* xF      = (const float*)d_in[0];
    const float* context = (const float*)d_in[1];
    const int*   perm    = (const int*)d_in[2];
    const float* Wq      = (const float*)d_in[3];
    const float* Wk      = (const float*)d_in[4];
    const float* Wv      = (const float*)d_in[5];
    const float* Wout    = (const float*)d_in[6];
    const float* b_out   = (const float*)d_in[7];
    float*       out     = (float*)d_out;

    const size_t WS_NEED = 71303168ULL;
    if (ws_size < WS_NEED) {
        hipMemsetAsync(d_out, 0, (size_t)out_size * sizeof(float), stream);
        return;
    }
    char* ws    = (char*)d_ws;
    u16* kbuf   = (u16*)(ws + 0);
    u16* vbufT  = (u16*)(ws + 2097152);
    u16* qbuf   = (u16*)(ws + 4194304);
    u16* ft     = qbuf;                         // aliased (see attn_mfma comment)
    u16* WoutT  = (u16*)(ws + 2097152);         // overwrites vbufT AFTER attn

    char* ob    = (char*)d_out;                 // d_out as pre-attn scratch
    u16* xb     = (u16*)(ob + 0);
    u16* cb     = (u16*)(ob + 33554432);
    u16* WkvT   = (u16*)(ob + 36700160);        // [1024][768]: rows 0-511 K, 512-1023 V
    u16* WqT    = (u16*)(ob + 38273024);

    // ---- prep: bf16 conversions / fused weight transposes ----
    convk<<<2048, 256, 0, stream>>>(xF, xb, N_PTS * CH_DIM / 8);
    convk<<<768, 256, 0, stream>>>(context, cb, BATCH * KTOK * CTX_DIM / 8);
    tconv3k<<<3584, 256, 0, stream>>>(Wq, Wk, Wv, WqT, WkvT);

    // ---- projections; Q pre-scaled by D^-0.5 * log2(e) (log2-domain softmax) ----
    gemm_bt<CH_DIM, false, false><<<dim3(HDIM / 128, N_PTS / 128), 256, 0, stream>>>(
        xb, WqT, qbuf, N_PTS, HDIM, nullptr, nullptr, 0.1803368801f);
    gemm_kv<<<dim3(16, 32), 256, 0, stream>>>(cb, WkvT, kbuf, vbufT);

    // ---- attention ----
    attn_mfma<<<dim3(NPB / 64, BATCH * NHEAD), 256, 0, stream>>>(
        qbuf, kbuf, vbufT, perm, ft);

    // ---- out projection (+bias+residual, fp32 out) ----
    tconvk<<<(HDIM * CH_DIM + 255) / 256, 256, 0, stream>>>(Wout, WoutT, HDIM, CH_DIM);
    gemm_bt<HDIM, true, false><<<dim3(CH_DIM / 128, N_PTS / 128), 256, 0, stream>>>(
        ft, WoutT, out, N_PTS, CH_DIM, b_out, xF, 1.0f);
}

// Round 6
// 282.328 us; speedup vs baseline: 1.0990x; 1.0990x over previous
//
#include <hip/hip_runtime.h>

typedef unsigned short u16;
typedef __attribute__((ext_vector_type(8))) short bf16x8;
typedef __attribute__((ext_vector_type(4))) float f32x4;
typedef __attribute__((ext_vector_type(4))) int i32x4;
typedef __attribute__((ext_vector_type(2))) int i32x2;

#define N_PTS   65536
#define CH_DIM  256
#define BATCH   8
#define KTOK    256
#define CTX_DIM 768
#define NHEAD   8
#define HD      64
#define HDIM    512   // NHEAD*HD
#define NPB     8192  // N_PTS/BATCH

__device__ __forceinline__ u16 f2bf(float f) {
    union { float f; unsigned u; } v; v.f = f;
    unsigned r = v.u + 0x7fffu + ((v.u >> 16) & 1u);
    return (u16)(r >> 16);
}
// HW packed f32->bf16 (RNE), 1 instr for a pair.
__device__ __forceinline__ unsigned cvtpk(float lo, float hi) {
    unsigned r;
    asm("v_cvt_pk_bf16_f32 %0, %1, %2" : "=v"(r) : "v"(lo), "v"(hi));
    return r;
}
// bare v_exp_f32 (base-2 exponential)
__device__ __forceinline__ float exp2_hw(float x) {
    float r;
    asm("v_exp_f32 %0, %1" : "=v"(r) : "v"(x));
    return r;
}
__device__ __forceinline__ float max3f(float a, float b, float c) {
    float r;
    asm("v_max3_f32 %0, %1, %2, %3" : "=v"(r) : "v"(a), "v"(b), "v"(c));
    return r;
}

// async global->LDS, 16B per lane. HW writes lane i at wave-uniform base + i*16.
__device__ __forceinline__ void gll16(const void* g, void* l) {
    __builtin_amdgcn_global_load_lds(
        (const __attribute__((address_space(1))) void*)g,
        (__attribute__((address_space(3))) void*)l, 16, 0, 0);
}

// ---------------------------------------------------------------------------
// convk: fp32 -> bf16, 8 elems/thread/iter, HW pack converts.
// ---------------------------------------------------------------------------
__global__ void convk(const float* __restrict__ src, u16* __restrict__ dst, int n8) {
    int i = blockIdx.x * blockDim.x + threadIdx.x;
    int st = gridDim.x * blockDim.x;
    for (; i < n8; i += st) {
        const float* p = src + (size_t)i * 8;
        f32x4 a = *(const f32x4*)p;
        f32x4 b = *(const f32x4*)(p + 4);
        i32x4 o;
        o[0] = (int)cvtpk(a[0], a[1]);
        o[1] = (int)cvtpk(a[2], a[3]);
        o[2] = (int)cvtpk(b[0], b[1]);
        o[3] = (int)cvtpk(b[2], b[3]);
        *(i32x4*)&dst[(size_t)i * 8] = o;
    }
}

// ---------------------------------------------------------------------------
// tconvk: W[R][C] fp32 -> WT[C][R] bf16. Flat: dst[i] = src[(i%R)*C + i/R].
// ---------------------------------------------------------------------------
__global__ void tconvk(const float* __restrict__ W, u16* __restrict__ WT, int R, int C) {
    int i = blockIdx.x * blockDim.x + threadIdx.x;
    if (i >= R * C) return;
    WT[i] = f2bf(W[(size_t)(i % R) * C + i / R]);
}

// tconv3k: fused Wq/Wk/Wv transpose+convert (one launch instead of three).
__global__ void tconv3k(const float* __restrict__ Wq, const float* __restrict__ Wk,
                        const float* __restrict__ Wv,
                        u16* __restrict__ WqT, u16* __restrict__ WkvT) {
    int i = blockIdx.x * blockDim.x + threadIdx.x;
    if (i < 131072) {
        WqT[i] = f2bf(Wq[(size_t)(i % 256) * 512 + i / 256]);
    } else if (i < 524288) {
        int j = i - 131072;
        WkvT[j] = f2bf(Wk[(size_t)(j % 768) * 512 + j / 768]);
    } else if (i < 917504) {
        int j = i - 524288;
        WkvT[393216 + j] = f2bf(Wv[(size_t)(j % 768) * 512 + j / 768]);
    }
}

// ---------------------------------------------------------------------------
// gemm_bt, 2-phase dbuf (best-measured loop form, R4): C = A(MxK) @ BT(NxK)^T.
// 128x128 tile, BK=32, 4 waves 2x2, 4x4 frags/wave, gll16 staging.
// SWAPPED MFMA: acc = mfma(bfr, af, acc) -> lane l15 indexes M (rows),
// reg r indexes N (4 consecutive cols). Epilogues are then VECTOR writes:
//   OUT_F32: f32x4 bias + f32x4 resid + f32x4 store (16 x 16B, was 64 scalars)
//   else:    2x v_cvt_pk_bf16_f32 + 8B store   (48 instrs, was ~580 VALU+64 st)
// (r5 post-mortem: GEMMs were epilogue-bound, not latency-bound; depth-3
//  counted-vmcnt regressed and is reverted.)
// T1 XCD swizzle: bijective remap (all grids here have nwg % 8 == 0).
// ---------------------------------------------------------------------------
template <int KC, bool OUT_F32>
__global__ __launch_bounds__(256, 3) void gemm_bt(
    const u16* __restrict__ A, const u16* __restrict__ BT, void* __restrict__ Cv,
    int M, int N,
    const float* __restrict__ bias, const float* __restrict__ resid, float oscale)
{
    __shared__ __align__(16) u16 As[2][128 * 32];   // 2 x 8 KB
    __shared__ __align__(16) u16 Bs[2][128 * 32];   // 2 x 8 KB

    const int tid  = threadIdx.x;
    const int lane = tid & 63;
    const int w    = tid >> 6;
    const int wm   = w & 1;
    const int wn   = w >> 1;

    const int nwg = gridDim.x * gridDim.y;
    const int wg  = blockIdx.y * gridDim.x + blockIdx.x;
    const int swz = (wg & 7) * (nwg >> 3) + (wg >> 3);
    const int n0  = (swz % gridDim.x) * 128;
    const int m0  = (swz / gridDim.x) * 128;

    const int l15  = lane & 15;
    const int quad = lane >> 4;

    f32x4 acc[4][4];
#pragma unroll
    for (int i = 0; i < 4; i++)
#pragma unroll
        for (int j = 0; j < 4; j++) { acc[i][j][0]=0.f; acc[i][j][1]=0.f; acc[i][j][2]=0.f; acc[i][j][3]=0.f; }

    const int sr = tid >> 2;
    const int sc = (tid & 3) * 8;
    const u16* Abase = A  + (size_t)(m0 + sr) * KC + sc;
    const u16* Bbase = BT + (size_t)(n0 + sr) * KC + sc;
    const size_t rowStep = (size_t)64 * KC;
    const int d8 = tid * 8;

    // ---- prologue: stage tile 0 into buffer 0 ----
    gll16(Abase,           &As[0][d8]);
    gll16(Abase + rowStep, &As[0][d8 + 2048]);
    gll16(Bbase,           &Bs[0][d8]);
    gll16(Bbase + rowStep, &Bs[0][d8 + 2048]);
    asm volatile("s_waitcnt vmcnt(0)" ::: "memory");
    __builtin_amdgcn_s_barrier();
    __builtin_amdgcn_sched_barrier(0);

    constexpr int ntile = KC >> 5;
    int cur = 0;
    for (int t = 0; t < ntile; ++t) {
        if (t + 1 < ntile) {                     // uniform branch
            const u16* An = Abase + ((t + 1) << 5);
            const u16* Bn = Bbase + ((t + 1) << 5);
            const int nxt = cur ^ 1;
            gll16(An,           &As[nxt][d8]);
            gll16(An + rowStep, &As[nxt][d8 + 2048]);
            gll16(Bn,           &Bs[nxt][d8]);
            gll16(Bn + rowStep, &Bs[nxt][d8 + 2048]);
        }
        bf16x8 af[4], bfr[4];
#pragma unroll
        for (int rt = 0; rt < 4; rt++)
            af[rt] = *(const bf16x8*)&As[cur][(wm * 64 + rt * 16 + l15) * 32 + quad * 8];
#pragma unroll
        for (int nt = 0; nt < 4; nt++)
            bfr[nt] = *(const bf16x8*)&Bs[cur][(wn * 64 + nt * 16 + l15) * 32 + quad * 8];
#pragma unroll
        for (int rt = 0; rt < 4; rt++)
#pragma unroll
            for (int nt = 0; nt < 4; nt++)   // SWAPPED: N on reg axis, M on lane axis
                acc[rt][nt] = __builtin_amdgcn_mfma_f32_16x16x32_bf16(bfr[nt], af[rt], acc[rt][nt], 0, 0, 0);
        asm volatile("s_waitcnt vmcnt(0)" ::: "memory");   // prefetch landed
        __builtin_amdgcn_sched_barrier(0);
        __builtin_amdgcn_s_barrier();                       // all waves done with buf[cur]
        __builtin_amdgcn_sched_barrier(0);
        cur ^= 1;
    }

    // ---- epilogue: acc[rt][nt][r] = C[m0+wm*64+rt*16+l15][n0+wn*64+nt*16+quad*4+r] ----
    if (OUT_F32) {
#pragma unroll
        for (int rt = 0; rt < 4; rt++) {
            int m = m0 + wm * 64 + rt * 16 + l15;
#pragma unroll
            for (int nt = 0; nt < 4; nt++) {
                int nb = n0 + wn * 64 + nt * 16 + quad * 4;
                f32x4 v  = acc[rt][nt];
                f32x4 bv = *(const f32x4*)&bias[nb];
                f32x4 rv = *(const f32x4*)&resid[(size_t)m * N + nb];
#pragma unroll
                for (int r = 0; r < 4; r++) v[r] += bv[r] + rv[r];
                *(f32x4*)&((float*)Cv)[(size_t)m * N + nb] = v;
            }
        }
    } else {
#pragma unroll
        for (int rt = 0; rt < 4; rt++) {
            int m = m0 + wm * 64 + rt * 16 + l15;
#pragma unroll
            for (int nt = 0; nt < 4; nt++) {
                int nb = n0 + wn * 64 + nt * 16 + quad * 4;
                union { unsigned u[2]; i32x2 q; } pk;
                pk.u[0] = cvtpk(acc[rt][nt][0] * oscale, acc[rt][nt][1] * oscale);
                pk.u[1] = cvtpk(acc[rt][nt][2] * oscale, acc[rt][nt][3] * oscale);
                *(i32x2*)&((u16*)Cv)[(size_t)m * N + nb] = pk.q;
            }
        }
    }
}

// ---------------------------------------------------------------------------
// gemm_kv: fused K-proj + V-proj (R4 2-phase form, unswapped -- V-half's
// transposed epilogue needs the row-on-reg-axis layout).
// A = cb [2048][768], BT = WkvT [1024][768] (rows 0..511 Wk, 512..1023 Wv).
// 64x64 tile, 4 waves 2x2, BK=32. Grid 16x32 = 512 blocks. Block-uniform
// epilogue: n0 < 512 -> kbuf; n0 >= 512 -> vbufT transposed+permuted.
// ---------------------------------------------------------------------------
__global__ __launch_bounds__(256, 4) void gemm_kv(
    const u16* __restrict__ A, const u16* __restrict__ BT,
    u16* __restrict__ kd, u16* __restrict__ vtd)
{
    __shared__ __align__(16) u16 As[2][64 * 32];   // 2 x 4 KB
    __shared__ __align__(16) u16 Bs[2][64 * 32];   // 2 x 4 KB
    const int K = CTX_DIM;

    const int tid  = threadIdx.x;
    const int lane = tid & 63;
    const int w    = tid >> 6;
    const int wm   = w & 1;
    const int wn   = w >> 1;

    const int nwg = gridDim.x * gridDim.y;          // 512
    const int wg  = blockIdx.y * gridDim.x + blockIdx.x;
    const int swz = (wg & 7) * (nwg >> 3) + (wg >> 3);
    const int n0  = (swz % gridDim.x) * 64;
    const int m0  = (swz / gridDim.x) * 64;

    const int l15  = lane & 15;
    const int quad = lane >> 4;

    f32x4 acc[2][2];
#pragma unroll
    for (int i = 0; i < 2; i++)
#pragma unroll
        for (int j = 0; j < 2; j++) { acc[i][j][0]=0.f; acc[i][j][1]=0.f; acc[i][j][2]=0.f; acc[i][j][3]=0.f; }

    const int sr = tid >> 2;          // 0..63
    const int sc = (tid & 3) * 8;
    const u16* Abase = A  + (size_t)(m0 + sr) * K + sc;
    const u16* Bbase = BT + (size_t)(n0 + sr) * K + sc;
    const int d8 = tid * 8;

    gll16(Abase, &As[0][d8]);
    gll16(Bbase, &Bs[0][d8]);
    asm volatile("s_waitcnt vmcnt(0)" ::: "memory");
    __builtin_amdgcn_s_barrier();
    __builtin_amdgcn_sched_barrier(0);

    const int ntile = K >> 5;   // 24
    int cur = 0;
    for (int t = 0; t < ntile; ++t) {
        if (t + 1 < ntile) {
            const int nxt = cur ^ 1;
            gll16(Abase + ((t + 1) << 5), &As[nxt][d8]);
            gll16(Bbase + ((t + 1) << 5), &Bs[nxt][d8]);
        }
        bf16x8 af[2], bfr[2];
#pragma unroll
        for (int rt = 0; rt < 2; rt++)
            af[rt] = *(const bf16x8*)&As[cur][(wm * 32 + rt * 16 + l15) * 32 + quad * 8];
#pragma unroll
        for (int nt = 0; nt < 2; nt++)
            bfr[nt] = *(const bf16x8*)&Bs[cur][(wn * 32 + nt * 16 + l15) * 32 + quad * 8];
#pragma unroll
        for (int rt = 0; rt < 2; rt++)
#pragma unroll
            for (int nt = 0; nt < 2; nt++)
                acc[rt][nt] = __builtin_amdgcn_mfma_f32_16x16x32_bf16(af[rt], bfr[nt], acc[rt][nt], 0, 0, 0);
        asm volatile("s_waitcnt vmcnt(0)" ::: "memory");
        __builtin_amdgcn_sched_barrier(0);
        __builtin_amdgcn_s_barrier();
        __builtin_amdgcn_sched_barrier(0);
        cur ^= 1;
    }

    if (n0 < 512) {   // ---- K half: plain bf16 [2048][512] ----
#pragma unroll
        for (int nt = 0; nt < 2; nt++) {
            int col = n0 + wn * 32 + nt * 16 + l15;
#pragma unroll
            for (int rt = 0; rt < 2; rt++) {
#pragma unroll
                for (int r = 0; r < 4; r++) {
                    int row = m0 + wm * 32 + rt * 16 + quad * 4 + r;
                    kd[(size_t)row * HDIM + col] = f2bf(acc[rt][nt][r]);
                }
            }
        }
    } else {          // ---- V half: transposed + permuted (attn PV layout) ----
#pragma unroll
        for (int nt = 0; nt < 2; nt++) {
            int col = (n0 - 512) + wn * 32 + nt * 16 + l15;   // h*64 + d
            int hh = col >> 6, dd = col & 63;
#pragma unroll
            for (int rt = 0; rt < 2; rt++) {
                int row = m0 + wm * 32 + rt * 16 + quad * 4;  // b*256 + t
                int bb = row >> 8, jb = row & 255;
                int jp = (jb & 0xE0) | ((jb & 0x0C) << 1) | ((jb & 0x10) >> 2);
                union { unsigned u[2]; i32x2 q; } pk;
                pk.u[0] = cvtpk(acc[rt][nt][0], acc[rt][nt][1]);
                pk.u[1] = cvtpk(acc[rt][nt][2], acc[rt][nt][3]);
                *(i32x2*)&vtd[(((size_t)(bb * 8 + hh)) * 64 + dd) * 256 + jp] = pk.q;
            }
        }
    }
}

// ---------------------------------------------------------------------------
// MFMA attention, zero-shuffle P path (unchanged; see r2/r3 notes).
// ---------------------------------------------------------------------------
#define KS2 72    // Ks row stride (u16)
#define VS2 264   // Vt row stride (u16)
__global__ __launch_bounds__(256, 4) void attn_mfma(
    const u16* qbuf, const u16* __restrict__ kbuf,
    const u16* __restrict__ vbufT, const int* __restrict__ perm,
    u16* ft)
{
    __shared__ __align__(16) u16 smem[18432];   // 36864 B
    u16* Ks = smem;                              // phase 1 (256 x KS2)
    u16* Vt = smem;                              // phase 3 (64 x VS2, reuse)

    const int tid   = threadIdx.x;
    const int lane  = tid & 63;
    const int w     = tid >> 6;
    const int chunk = blockIdx.x;
    const int bh    = blockIdx.y;
    const int b     = bh >> 3;
    const int h     = bh & 7;
    const int l15   = lane & 15;
    const int quad  = lane >> 4;

    // ---- Q B-frags from global (gathered row, 16B contiguous); q = w*16+l15 ----
    const int prow = perm[b * NPB + chunk * 64 + w * 16 + l15];
    const u16* qrow = qbuf + (size_t)prow * HDIM + h * HD;
    bf16x8 qf0 = *(const bf16x8*)&qrow[quad * 8];
    bf16x8 qf1 = *(const bf16x8*)&qrow[32 + quad * 8];

    // ---- stage K_h (256x64) into LDS, b128 writes ----
    {
        const int j8 = tid >> 3;        // 0..31
        const int c  = (tid & 7) * 8;   // 0..56
#pragma unroll
        for (int pass = 0; pass < 8; pass++) {
            int jj = j8 + pass * 32;
            i32x4 val = *(const i32x4*)&kbuf[((size_t)(b * KTOK + jj)) * HDIM + h * HD + c];
            *(i32x4*)&Ks[jj * KS2 + c] = val;
        }
    }
    __syncthreads();

    // ---- phase 1: S^T = K @ Q^T ----
    f32x4 sc[16];
#pragma unroll
    for (int nt = 0; nt < 16; nt++) { sc[nt][0]=0.f; sc[nt][1]=0.f; sc[nt][2]=0.f; sc[nt][3]=0.f; }
#pragma unroll
    for (int nt = 0; nt < 16; nt++) {
        bf16x8 kf = *(const bf16x8*)&Ks[(nt * 16 + l15) * KS2 + quad * 8];
        sc[nt] = __builtin_amdgcn_mfma_f32_16x16x32_bf16(kf, qf0, sc[nt], 0, 0, 0);
    }
#pragma unroll
    for (int nt = 0; nt < 16; nt++) {
        bf16x8 kf = *(const bf16x8*)&Ks[(nt * 16 + l15) * KS2 + 32 + quad * 8];
        sc[nt] = __builtin_amdgcn_mfma_f32_16x16x32_bf16(kf, qf1, sc[nt], 0, 0, 0);
    }
    // sc[nt][r] = S'[k = nt*16 + quad*4 + r][q = w*16 + l15]  (log2-domain)

    // ---- phase 3a: issue V' loads to regs; latency hides under softmax ----
    i32x4 vreg[8];
    const u16* vslice = vbufT + ((size_t)(b * NHEAD + h)) * HD * KTOK;
    const int vrow = tid >> 2;          // d = 0..63
    const int vc0  = (tid & 3) * 8;
#pragma unroll
    for (int pass = 0; pass < 8; pass++)
        vreg[pass] = *(const i32x4*)&vslice[(size_t)vrow * KTOK + vc0 + pass * 32];

    // ---- phase 2: softmax (log2 domain), lane-local; deferred 1/s ----
    float m = -1e30f;
#pragma unroll
    for (int nt = 0; nt < 16; nt++) {
        f32x4 v = sc[nt];
        m = max3f(m, max3f(v[0], v[1], v[2]), v[3]);
    }
    m = fmaxf(m, __shfl_xor(m, 16));
    m = fmaxf(m, __shfl_xor(m, 32));
    float s0 = 0.f, s1 = 0.f, s2 = 0.f, s3 = 0.f;
#pragma unroll
    for (int nt = 0; nt < 16; nt++) {
        float e0 = exp2_hw(sc[nt][0] - m);
        float e1 = exp2_hw(sc[nt][1] - m);
        float e2 = exp2_hw(sc[nt][2] - m);
        float e3 = exp2_hw(sc[nt][3] - m);
        sc[nt][0] = e0; sc[nt][1] = e1; sc[nt][2] = e2; sc[nt][3] = e3;
        s0 += e0; s1 += e1; s2 += e2; s3 += e3;
    }
    float s = (s0 + s1) + (s2 + s3);
    s += __shfl_xor(s, 16);
    s += __shfl_xor(s, 32);
    float inv = 1.0f / s;

    // ---- pack P to bf16 pairs in-register (HW cvt_pk) ----
    unsigned up[16][2];
#pragma unroll
    for (int nt = 0; nt < 16; nt++) {
        up[nt][0] = cvtpk(sc[nt][0], sc[nt][1]);
        up[nt][1] = cvtpk(sc[nt][2], sc[nt][3]);
    }

    __syncthreads();   // all waves done reading Ks; region becomes Vt'

    // ---- phase 3b: store Vt' rows to LDS (contiguous b128) ----
#pragma unroll
    for (int pass = 0; pass < 8; pass++)
        *(i32x4*)&Vt[vrow * VS2 + vc0 + pass * 32] = vreg[pass];
    __syncthreads();

    // ---- phase 4: O = P V (A = P regs, B = Vt' b128 reads; 32 MFMA) ----
    f32x4 o[4];
#pragma unroll
    for (int n = 0; n < 4; n++) { o[n][0]=0.f; o[n][1]=0.f; o[n][2]=0.f; o[n][3]=0.f; }

#pragma unroll
    for (int ks = 0; ks < 8; ks++) {
        union { unsigned u[4]; bf16x8 v; } pb;
        pb.u[0] = up[2 * ks][0];
        pb.u[1] = up[2 * ks][1];
        pb.u[2] = up[2 * ks + 1][0];
        pb.u[3] = up[2 * ks + 1][1];
#pragma unroll
        for (int nt = 0; nt < 4; nt++) {
            bf16x8 bv = *(const bf16x8*)&Vt[(nt * 16 + l15) * VS2 + ks * 32 + quad * 8];
            o[nt] = __builtin_amdgcn_mfma_f32_16x16x32_bf16(pb.v, bv, o[nt], 0, 0, 0);
        }
    }
    // o[nt][r] = O~[q = w*16 + quad*4 + r][d = nt*16 + l15]  (unnormalized)

    // ---- phase 5: normalize + scatter O rows to ft[perm[q]] ----
#pragma unroll
    for (int r = 0; r < 4; r++) {
        float invq = __shfl(inv,  quad * 4 + r);
        int   po   = __shfl(prow, quad * 4 + r);
        u16* frow = ft + (size_t)po * HDIM + h * HD;
        unsigned pa = cvtpk(o[0][r] * invq, o[1][r] * invq);
        unsigned pb = cvtpk(o[2][r] * invq, o[3][r] * invq);
        frow[l15]      = (u16)pa;
        frow[16 + l15] = (u16)(pa >> 16);
        frow[32 + l15] = (u16)pb;
        frow[48 + l15] = (u16)(pb >> 16);
    }
}

// ---------------------------------------------------------------------------
// Launch. Workspace (unchanged 71303168 B):
//   ws+0        kbuf  [2048][512] bf16          (2 MB)
//   ws+2097152  vbufT [b][h][d][c'] bf16        (2 MB)  -> WoutT after attn
//   ws+4194304  qbuf/ft [65536][512] bf16       (67 MB)
// Scratch in d_out (all dead before the final gemm writes d_out):
//   +0         xb   [65536][256] bf16  (33554432)
//   +33554432  cb   [2048][768]  bf16  (3145728, ends 36700160)
//   +36700160  WkvT [1024][768]  bf16  (1572864, ends 38273024)
//   +38273024  WqT  [512][256]   bf16  (262144,  ends 38535168 < 67108864)
// ---------------------------------------------------------------------------
extern "C" void kernel_launch(void* const* d_in, const int* in_sizes, int n_in,
                              void* d_out, int out_size, void* d_ws, size_t ws_size,
                              hipStream_t stream) {
    const float* xF      = (const float*)d_in[0];
    const float* context = (const float*)d_in[1];
    const int*   perm    = (const int*)d_in[2];
    const float* Wq      = (const float*)d_in[3];
    const float* Wk      = (const float*)d_in[4];
    const float* Wv      = (const float*)d_in[5];
    const float* Wout    = (const float*)d_in[6];
    const float* b_out   = (const float*)d_in[7];
    float*       out     = (float*)d_out;

    const size_t WS_NEED = 71303168ULL;
    if (ws_size < WS_NEED) {
        hipMemsetAsync(d_out, 0, (size_t)out_size * sizeof(float), stream);
        return;
    }
    char* ws    = (char*)d_ws;
    u16* kbuf   = (u16*)(ws + 0);
    u16* vbufT  = (u16*)(ws + 2097152);
    u16* qbuf   = (u16*)(ws + 4194304);
    u16* ft     = qbuf;                         // aliased (see attn_mfma comment)
    u16* WoutT  = (u16*)(ws + 2097152);         // overwrites vbufT AFTER attn

    char* ob    = (char*)d_out;                 // d_out as pre-attn scratch
    u16* xb     = (u16*)(ob + 0);
    u16* cb     = (u16*)(ob + 33554432);
    u16* WkvT   = (u16*)(ob + 36700160);        // [1024][768]: rows 0-511 K, 512-1023 V
    u16* WqT    = (u16*)(ob + 38273024);

    // ---- prep: bf16 conversions / fused weight transposes ----
    convk<<<2048, 256, 0, stream>>>(xF, xb, N_PTS * CH_DIM / 8);
    convk<<<768, 256, 0, stream>>>(context, cb, BATCH * KTOK * CTX_DIM / 8);
    tconv3k<<<3584, 256, 0, stream>>>(Wq, Wk, Wv, WqT, WkvT);

    // ---- projections; Q pre-scaled by D^-0.5 * log2(e) (log2-domain softmax) ----
    gemm_bt<CH_DIM, false><<<dim3(HDIM / 128, N_PTS / 128), 256, 0, stream>>>(
        xb, WqT, qbuf, N_PTS, HDIM, nullptr, nullptr, 0.1803368801f);
    gemm_kv<<<dim3(16, 32), 256, 0, stream>>>(cb, WkvT, kbuf, vbufT);

    // ---- attention ----
    attn_mfma<<<dim3(NPB / 64, BATCH * NHEAD), 256, 0, stream>>>(
        qbuf, kbuf, vbufT, perm, ft);

    // ---- out projection (+bias+residual, fp32 out) ----
    tconvk<<<(HDIM * CH_DIM + 255) / 256, 256, 0, stream>>>(Wout, WoutT, HDIM, CH_DIM);
    gemm_bt<HDIM, true><<<dim3(CH_DIM / 128, N_PTS / 128), 256, 0, stream>>>(
        ft, WoutT, out, N_PTS, CH_DIM, b_out, xF, 1.0f);
}